// Round 4
// baseline (229.704 us; speedup 1.0000x reference)
//
#include <hip/hip_runtime.h>
#include <hip/hip_bf16.h>

// SoftMoEGating: B=8, S=4096, D=1024, E=8, P=4, K=E*P=32
#define B 8
#define S 4096
#define DD 1024
#define KK 32

typedef __attribute__((ext_vector_type(8))) short bf16x8;
typedef __attribute__((ext_vector_type(16))) float f32x16;

static __device__ __forceinline__ unsigned short f2bf(float f) {
    unsigned int u = __builtin_bit_cast(unsigned int, f);
    u += 0x7FFFu + ((u >> 16) & 1u);     // RNE
    return (unsigned short)(u >> 16);
}

static __device__ __forceinline__ unsigned int pack2bf(float lo, float hi) {
    return (unsigned int)f2bf(lo) | ((unsigned int)f2bf(hi) << 16);
}

// ---------------------------------------------------------------------------
// K0: phi [1024 d][32 k] fp32  ->  phiT [32 k][1024 d] bf16 (B-operand layout).
// ---------------------------------------------------------------------------
__global__ __launch_bounds__(256) void k0_phit(const float* __restrict__ phi,
                                               unsigned short* __restrict__ phiT) {
    __shared__ float lt[32][33];
    const int d0 = blockIdx.x * 32;
    const int tid = threadIdx.x;
#pragma unroll
    for (int i = 0; i < 4; ++i) {
        int slot = tid + i * 256;
        int d = slot >> 5, k = slot & 31;
        lt[d][k] = phi[(size_t)(d0 + d) * KK + k];
    }
    __syncthreads();
    const int k = tid >> 3, c = tid & 7, d = c * 4;
    short4 pk;
    pk.x = (short)f2bf(lt[d + 0][k]);
    pk.y = (short)f2bf(lt[d + 1][k]);
    pk.z = (short)f2bf(lt[d + 2][k]);
    pk.w = (short)f2bf(lt[d + 3][k]);
    *(short4*)(phiT + (size_t)k * DD + d0 + d) = pk;
}

// ---------------------------------------------------------------------------
// K1: logits. grid = 8b x 64 stile(64 s) = 512 blocks -> 2 blocks/CU.
// 4 waves: (wv>>1 = row-group of 32 tokens, wv&1 = d-half of 512). phiT
// fully LDS-resident (64 KB, swizzled). A-frags straight from global.
// Epilogue: d-half partial sums combined through LDS, coalesced k-major lp
// store + fused per-64-token softmax partials (max, sum-exp). (unchanged)
// ---------------------------------------------------------------------------
__global__ __launch_bounds__(256) void k1_logits(const float* __restrict__ x,
                                                 const unsigned short* __restrict__ phiT,
                                                 const float* __restrict__ bias,
                                                 float* __restrict__ lp,
                                                 float* __restrict__ pmax,
                                                 float* __restrict__ psum) {
    __shared__ __align__(16) char sm[65536];   // phiT tile; lt overlays later

    const int bid = blockIdx.x;
    const int st = bid & 63;
    const int b  = bid >> 6;
    const int tid = threadIdx.x;
    const int wv = __builtin_amdgcn_readfirstlane(tid >> 6);
    const int lane = tid & 63;
    const int l31 = lane & 31;
    const int half = lane >> 5;
    const int r0 = (wv >> 1) * 32;   // token row group within 64
    const int h  = wv & 1;           // d-half

    // stage phiT [32 k][1024 d] bf16 = 64 KB, 16B-block XOR swizzle (per k)
    {
        const uint4* pg = (const uint4*)phiT;   // 128 uint4 per k-row
#pragma unroll
        for (int i = 0; i < 16; ++i) {
            int slot = tid + i * 256;
            int k = slot >> 7, blk = slot & 127;
            uint4 v = pg[(size_t)k * 128 + blk];
            *(uint4*)(sm + (size_t)k * 2048 + ((blk ^ (k & 7)) << 4)) = v;
        }
    }

    f32x16 acc;
    {
        float bv = (h == 0) ? bias[l31] : 0.f;   // bias once per (token,k)
#pragma unroll
        for (int r = 0; r < 16; ++r) acc[r] = bv;
    }
    __syncthreads();

    // A: token row = st*64 + r0 + l31; d-cols = h*512 + ch*16 + half*8 + j
    const float* xg = x + ((size_t)(b * S + st * 64 + r0 + l31)) * DD
                        + h * 512 + half * 8;
    const int kx = l31 & 7;
    const char* brow = sm + (size_t)l31 * 2048;

#pragma unroll 8
    for (int ch = 0; ch < 32; ++ch) {
        float4 a0 = *(const float4*)(xg + ch * 16);
        float4 a1 = *(const float4*)(xg + ch * 16 + 4);
        unsigned int p0 = pack2bf(a0.x, a0.y);
        unsigned int p1 = pack2bf(a0.z, a0.w);
        unsigned int p2 = pack2bf(a1.x, a1.y);
        unsigned int p3 = pack2bf(a1.z, a1.w);
        uint4 pv = make_uint4(p0, p1, p2, p3);
        bf16x8 af = __builtin_bit_cast(bf16x8, pv);
        int blk = h * 64 + ch * 2 + half;
        bf16x8 bfv = *(const bf16x8*)(brow + ((blk ^ kx) << 4));
        acc = __builtin_amdgcn_mfma_f32_32x32x16_bf16(af, bfv, acc, 0, 0, 0);
    }

    __syncthreads();                       // all MFMAs done; phiT tile is dead
    float* lt = (float*)sm;                // [32 k][65 s] fp32 (8.3 KB)
    if (h == 0) {
#pragma unroll
        for (int r = 0; r < 16; ++r) {
            int row = (r & 3) + 8 * (r >> 2) + 4 * half;   // token row in 32
            lt[(size_t)l31 * 65 + r0 + row] = acc[r];
        }
    }
    __syncthreads();
    if (h == 1) {
#pragma unroll
        for (int r = 0; r < 16; ++r) {
            int row = (r & 3) + 8 * (r >> 2) + 4 * half;
            lt[(size_t)l31 * 65 + r0 + row] += acc[r];
        }
    }
    __syncthreads();

    // coalesced k-major lp store (32 k x 64 s = 512 float4)
    float* o = lp + ((size_t)b * KK) * S + st * 64;
#pragma unroll
    for (int i = 0; i < 2; ++i) {
        int slot = tid + i * 256;
        int k = slot >> 4, s4 = slot & 15;
        float4 v;
        v.x = lt[k * 65 + s4 * 4 + 0];
        v.y = lt[k * 65 + s4 * 4 + 1];
        v.z = lt[k * 65 + s4 * 4 + 2];
        v.w = lt[k * 65 + s4 * 4 + 3];
        *(float4*)(o + (size_t)k * S + s4 * 4) = v;
    }

    // fused softmax partials: k = tid>>3, 8 lanes x 8 tokens each
    const int pk = tid >> 3, pj = tid & 7;
    const float* lr = lt + (size_t)pk * 65 + pj * 8;
    float m = lr[0];
#pragma unroll
    for (int i = 1; i < 8; ++i) m = fmaxf(m, lr[i]);
#pragma unroll
    for (int off = 4; off >= 1; off >>= 1) m = fmaxf(m, __shfl_xor(m, off, 64));
    float l = 0.f;
#pragma unroll
    for (int i = 0; i < 8; ++i) l += __expf(lr[i] - m);
#pragma unroll
    for (int off = 4; off >= 1; off >>= 1) l += __shfl_xor(l, off, 64);
    if (pj == 0) {
        pmax[((size_t)b * KK + pk) * 64 + st] = m;
        psum[((size_t)b * KK + pk) * 64 + st] = l;
    }
}

// ---------------------------------------------------------------------------
// K2c: combine 64 partials (8 lanes/k, shfl-merged), normalize; write wbT
// bf16 [b][k][s] AND pw fp32 [b][s][k] via LDS transpose. grid = B*32.
// (unchanged)
// ---------------------------------------------------------------------------
__global__ __launch_bounds__(256) void k2c_norm(const float* __restrict__ lp,
                                                const float* __restrict__ pmax,
                                                const float* __restrict__ psum,
                                                unsigned short* __restrict__ wbT,
                                                float* __restrict__ pw_out) {
    __shared__ float tile[128][33];
    __shared__ float sM[32], sLinv[32];
    const int b  = blockIdx.x >> 5;
    const int sc = blockIdx.x & 31;
    const int s0 = sc * 128;
    const int tid = threadIdx.x;

    {   // 32 k x 8 lanes; each lane merges 8 chunks, then shfl tree-merge
        const int k = tid >> 3, pj = tid & 7;
        float M = -1e30f, L = 0.f;
#pragma unroll
        for (int c = 0; c < 8; ++c) {
            int cc = pj * 8 + c;
            float mc = pmax[((size_t)b * KK + k) * 64 + cc];
            float lc = psum[((size_t)b * KK + k) * 64 + cc];
            float nM = fmaxf(M, mc);
            L = L * __expf(M - nM) + lc * __expf(mc - nM);
            M = nM;
        }
#pragma unroll
        for (int off = 4; off >= 1; off >>= 1) {
            float Mo = __shfl_xor(M, off, 64);
            float Lo = __shfl_xor(L, off, 64);
            float nM = fmaxf(M, Mo);
            L = L * __expf(M - nM) + Lo * __expf(Mo - nM);
            M = nM;
        }
        if (pj == 0) {
            sM[k] = M;
            sLinv[k] = 1.0f / L;
        }
    }
    __syncthreads();

    const int sL = tid & 127;
    const int kh = tid >> 7;
#pragma unroll
    for (int kk = 0; kk < 16; ++kk) {
        const int k = kk * 2 + kh;
        const size_t idx = ((size_t)b * KK + k) * S + s0 + sL;
        float v = lp[idx];
        float w = __expf(v - sM[k]) * sLinv[k];
        wbT[idx] = f2bf(w);
        tile[sL][k] = w;
    }
    __syncthreads();

    float* ob = pw_out + ((size_t)b * S + s0) * KK;
#pragma unroll
    for (int i = 0; i < 4; ++i) {
        const int idx4 = tid + i * 256;
        const int sl = idx4 >> 3, kq = idx4 & 7;
        float4 v4 = make_float4(tile[sl][kq * 4 + 0], tile[sl][kq * 4 + 1],
                                tile[sl][kq * 4 + 2], tile[sl][kq * 4 + 3]);
        ((float4*)ob)[idx4] = v4;
    }
}

// ---------------------------------------------------------------------------
// K3: soft_slots via MFMA 32x32x16 bf16: C[k][d] = sum_s w[k][s] x[s][d].
// grid = 8b x 8 dg(128 d) x 8 sc(512 s) = 512, 4 waves.
// NEW: fully LDS-free, zero barriers. x has zero intra-block reuse (B-frag
// reuse over 32 k is internal to the MFMA) -> B-frags loaded straight from
// global: for fixed j, lanes 0-31 read 128 contiguous bytes (consecutive d,
// fixed s) -> perfectly coalesced. A-frags (w[k=l31][s..s+8]) are one
// contiguous dwordx4 from global; wbT is 2 MB (L2/L3-resident; the 8
// dg-blocks sharing a w-slice land on one XCD since their bids differ by 8).
// __launch_bounds__(256,4): VGPR<=128 -> 4 blocks/CU (vs 2 with LDS dbuf).
// ---------------------------------------------------------------------------
__global__ __launch_bounds__(256, 4) void k3_slots(const float* __restrict__ x,
                                                   const unsigned short* __restrict__ wbT,
                                                   float* __restrict__ part) {
    const int bid = blockIdx.x;
    const int sc = bid & 7;
    const int dg = (bid >> 3) & 7;
    const int b  = bid >> 6;
    const int tid = threadIdx.x;
    const int wv = __builtin_amdgcn_readfirstlane(tid >> 6);
    const int lane = tid & 63;
    const int l31 = lane & 31;
    const int half = lane >> 5;
    const int col = wv * 32 + l31;   // d-col within 128-d tile

    // B-frag base: x[s = sc*512 + half*8][d = dg*128 + col]
    const float* xg = x + ((size_t)(b * S + sc * 512 + half * 8)) * DD + dg * 128 + col;
    // A-frag base: w[k = l31][s = sc*512 + half*8]  (contiguous 16 B)
    const unsigned short* wg = wbT + ((size_t)(b * KK + l31)) * S + sc * 512 + half * 8;

    f32x16 acc;
#pragma unroll
    for (int r = 0; r < 16; ++r) acc[r] = 0.f;

#pragma unroll 4
    for (int t = 0; t < 32; ++t) {
        const int sb = t * 16;                    // s-block base (half*8 folded)
        bf16x8 af = *(const bf16x8*)(wg + sb);
        const float* xp = xg + (size_t)sb * DD;
        unsigned int p0 = pack2bf(xp[0],               xp[(size_t)1 * DD]);
        unsigned int p1 = pack2bf(xp[(size_t)2 * DD],  xp[(size_t)3 * DD]);
        unsigned int p2 = pack2bf(xp[(size_t)4 * DD],  xp[(size_t)5 * DD]);
        unsigned int p3 = pack2bf(xp[(size_t)6 * DD],  xp[(size_t)7 * DD]);
        uint4 pv = make_uint4(p0, p1, p2, p3);
        bf16x8 bfv = __builtin_bit_cast(bf16x8, pv);
        acc = __builtin_amdgcn_mfma_f32_32x32x16_bf16(af, bfv, acc, 0, 0, 0);
    }

    float* pp = part + (((size_t)sc * B + b) * KK) * DD + dg * 128 + col;
#pragma unroll
    for (int r = 0; r < 16; ++r) {
        int k = (r & 3) + 8 * (r >> 2) + 4 * half;
        pp[(size_t)k * DD] = acc[r];
    }
}

// ---------------------------------------------------------------------------
// K4: reduce 8 partials -> soft_slots + expert_inputs; fill expert_weights
// and expert_indices. grid 256. (unchanged)
// ---------------------------------------------------------------------------
__global__ __launch_bounds__(256) void k4_finalize(const float* __restrict__ part,
                                                   float* __restrict__ out) {
    const int idx = blockIdx.x * 256 + threadIdx.x;
    const float4* p4 = (const float4*)part;

    float4 sv = p4[idx];
#pragma unroll
    for (int c = 1; c < 8; ++c) {
        float4 t = p4[(size_t)c * 65536 + idx];
        sv.x += t.x; sv.y += t.y; sv.z += t.z; sv.w += t.w;
    }

    ((float4*)(out + 1572864))[idx] = sv;
    ((float4*)(out + 1835008))[idx] = sv;
    ((float4*)out)[idx] = make_float4(0.125f, 0.125f, 0.125f, 0.125f);
    float base = (float)((idx * 4) & 7);
    ((float4*)(out + 262144))[idx] = make_float4(base, base + 1.f, base + 2.f, base + 3.f);
}

extern "C" void kernel_launch(void* const* d_in, const int* in_sizes, int n_in,
                              void* d_out, int out_size, void* d_ws, size_t ws_size,
                              hipStream_t stream) {
    const float* x    = (const float*)d_in[0];
    const float* phi  = (const float*)d_in[1];
    const float* bias = (const float*)d_in[2];
    float* out = (float*)d_out;

    // ws layout (float units):
    //   lp    @ 0        (1048576: [b][k][s], bias included)
    //   pmax  @ 1048576  (16384: [b][k][64 chunks])
    //   psum  @ 1064960  (16384)
    //   wbT   @ 1081344  (1048576 u16 = 524288 f)
    //   phiT  @ 1605632  (32768 u16 = 16384 f)
    //   part  @ 1622016  (8 x 262144)
    float* ws = (float*)d_ws;
    float* lp   = ws;
    float* pmax = ws + 1048576;
    float* psum = ws + 1064960;
    unsigned short* wbT  = (unsigned short*)(ws + 1081344);
    unsigned short* phiT = (unsigned short*)(ws + 1605632);
    float* part = ws + 1622016;
    float* pw_out = out + 524288;

    k0_phit<<<dim3(32), dim3(256), 0, stream>>>(phi, phiT);
    k1_logits<<<dim3(512), dim3(256), 0, stream>>>(x, phiT, bias, lp, pmax, psum);
    k2c_norm<<<dim3(256), dim3(256), 0, stream>>>(lp, pmax, psum, wbT, pw_out);
    k3_slots<<<dim3(512), dim3(256), 0, stream>>>(x, wbT, part);
    k4_finalize<<<dim3(256), dim3(256), 0, stream>>>(part, out);
}